// Round 7
// baseline (574.528 us; speedup 1.0000x reference)
//
#include <hip/hip_runtime.h>

#define E_TOT 160000
#define TPB   64
#define NBLK  2500       // 2500*64 == 160000 exactly; 9.8 blocks/CU (grid-limited occupancy)
#define ARENA 57         // f32 words/thread: h[0..31] (h1 then h2) | msg1[32..55] | pad

struct P4 { const float *w1, *b1, *w2, *b2, *w3, *b3; };

__global__ __launch_bounds__(TPB, 4) void edge_kernel(
    const float* __restrict__ feat0, const float* __restrict__ feat1,
    const float* __restrict__ wE,    const float* __restrict__ radial,
    const float* __restrict__ b00,   const float* __restrict__ b01,
    const float* __restrict__ b10,   const float* __restrict__ b11,
    const int* __restrict__ src_idx,
    P4 W0, P4 W1, P4 W2, P4 W3,
    float* __restrict__ out)
{
  __shared__ float lds[TPB * ARENA];               // 14,592 B -> LDS never the occupancy limit
  const int tid = threadIdx.x;
  const int e = blockIdx.x * TPB + tid;
  float* A = lds + tid * ARENA;                    // stride 57 (odd): 2-way aliasing = free
  const int phase = blockIdx.x & 3;                // stagger weight streams across waves

  // ---- per-edge scalars ----
  const float bB = b00[e];
  float B01[3], B10[3];
  #pragma unroll
  for (int q = 0; q < 3; ++q){
    B01[q] = b01[(size_t)e*3 + q];
    B10[q] = b10[(size_t)e*3 + q];
  }

  // ---- edge features in registers (layer-1 fully unrolled -> static indexing) ----
  float ef[17];
  {
    const float4* wp = (const float4*)(wE + (size_t)e * 16);
    float4 a = wp[0], b = wp[1], c = wp[2], d = wp[3];
    ef[0]=a.x;  ef[1]=a.y;  ef[2]=a.z;  ef[3]=a.w;
    ef[4]=b.x;  ef[5]=b.y;  ef[6]=b.z;  ef[7]=b.w;
    ef[8]=c.x;  ef[9]=c.y;  ef[10]=c.z; ef[11]=c.w;
    ef[12]=d.x; ef[13]=d.y; ef[14]=d.z; ef[15]=d.w;
    ef[16] = radial[e];
  }
  // ---- source features ----
  const int idx = src_idx[e];
  float s0[8], s1[24];
  {
    const float4* f0 = (const float4*)(feat0 + (size_t)idx * 8);
    float4 a = f0[0], b = f0[1];
    s0[0]=a.x; s0[1]=a.y; s0[2]=a.z; s0[3]=a.w;
    s0[4]=b.x; s0[5]=b.y; s0[6]=b.z; s0[7]=b.w;
    const float4* f1 = (const float4*)(feat1 + (size_t)idx * 24);
    #pragma unroll
    for (int j = 0; j < 6; ++j){
      float4 v = f1[j];
      s1[4*j+0]=v.x; s1[4*j+1]=v.y; s1[4*j+2]=v.z; s1[4*j+3]=v.w;
    }
  }
  // U[i] = sum_q B10[q]*s1[i,q]
  float U[8];
  #pragma unroll
  for (int i = 0; i < 8; ++i)
    U[i] = fmaf(B10[0], s1[3*i+0], fmaf(B10[1], s1[3*i+1], B10[2]*s1[3*i+2]));

  float msg0[8];
  #pragma unroll
  for (int o = 0; o < 8; ++o) msg0[o] = 0.f;
  #pragma unroll
  for (int j = 0; j < 24; ++j) A[32 + j] = 0.f;    // msg1 accumulator (order-free adds)

  // ================= rotated phase loop =================
  #pragma unroll 1
  for (int pp = 0; pp < 4; ++pp){
    const int p = (pp + phase) & 3;
    const float* __restrict__ w1 = (p==0)?W0.w1:(p==1)?W1.w1:(p==2)?W2.w1:W3.w1;
    const float* __restrict__ b1 = (p==0)?W0.b1:(p==1)?W1.b1:(p==2)?W2.b1:W3.b1;
    const float* __restrict__ w2 = (p==0)?W0.w2:(p==1)?W1.w2:(p==2)?W2.w2:W3.w2;
    const float* __restrict__ b2 = (p==0)?W0.b2:(p==1)?W1.b2:(p==2)?W2.b2:W3.b2;
    const float* __restrict__ w3 = (p==0)?W0.w3:(p==1)?W1.w3:(p==2)?W2.w3:W3.w3;
    const float* __restrict__ b3 = (p==0)?W0.b3:(p==1)?W1.b3:(p==2)?W2.b3:W3.b3;

    // ---------- radial MLP: ef(regs) -> h1(LDS) -> h2(LDS A[0..31]) ----------
    {
      float h[32];
      #pragma unroll
      for (int m = 0; m < 32; ++m) h[m] = b1[m];
      #pragma unroll
      for (int k = 0; k < 17; ++k){                // fully unrolled: ef static
        const float* __restrict__ r = w1 + k * 32;
        #pragma unroll
        for (int m = 0; m < 32; ++m) h[m] = fmaf(ef[k], r[m], h[m]);
      }
      #pragma unroll
      for (int m = 0; m < 32; ++m) A[m] = fmaxf(h[m], 0.f);
      float g[32];
      #pragma unroll
      for (int m = 0; m < 32; ++m) g[m] = b2[m];
      #pragma unroll 1
      for (int c = 0; c < 4; ++c){                 // k-chunks of 8 (h1 from LDS)
        float x[8];
        #pragma unroll
        for (int j = 0; j < 8; ++j) x[j] = A[c*8 + j];
        const float* __restrict__ r = w2 + c * 256;
        #pragma unroll
        for (int j = 0; j < 8; ++j){
          #pragma unroll
          for (int m = 0; m < 32; ++m) g[m] = fmaf(x[j], r[j*32 + m], g[m]);
        }
      }
      #pragma unroll
      for (int m = 0; m < 32; ++m) A[m] = fmaxf(g[m], 0.f);     // h2 replaces h1
    }

    if (p < 3){
      // ---------- layer-3 matvec, 64 cols ----------
      float v[8];
      #pragma unroll
      for (int i = 0; i < 8; ++i) v[i] = (p == 2) ? U[i] : s0[i];
      float acc[8];
      #pragma unroll
      for (int o = 0; o < 8; ++o){
        float t = 0.f;
        #pragma unroll
        for (int i = 0; i < 8; ++i) t = fmaf(b3[o*8 + i], v[i], t);
        acc[o] = t;
      }
      #pragma unroll 1
      for (int c = 0; c < 4; ++c){                 // m-chunks of 8
        float hh[8];
        #pragma unroll
        for (int j = 0; j < 8; ++j) hh[j] = A[c*8 + j];
        const float* __restrict__ rb = w3 + c * 512;
        #pragma unroll
        for (int j = 0; j < 8; ++j){
          const float* __restrict__ r = rb + j * 64;
          #pragma unroll
          for (int o = 0; o < 8; ++o){
            float t = 0.f;
            #pragma unroll
            for (int i = 0; i < 8; ++i) t = fmaf(r[o*8 + i], v[i], t);
            acc[o] = fmaf(hh[j], t, acc[o]);
          }
        }
      }
      if (p == 0){
        #pragma unroll
        for (int o = 0; o < 8; ++o) msg0[o] = fmaf(acc[o], bB, msg0[o]);
      } else if (p == 2){
        #pragma unroll
        for (int o = 0; o < 8; ++o) msg0[o] += acc[o];
      } else {                                     // p == 1: rank-1 term into msg1 buffer
        #pragma unroll
        for (int o = 0; o < 8; ++o){
          #pragma unroll
          for (int q = 0; q < 3; ++q)
            A[32 + o*3 + q] += acc[o] * B01[q];    // static indices
        }
      }
    } else {
      // ---------- pair (1,1): per-o R-slice + D-contraction, into msg1 buffer ------
      float Bv[27];
      const float* __restrict__ bp = b11 + (size_t)e * 27;   // [p][q][f]
      #pragma unroll
      for (int j = 0; j < 27; ++j) Bv[j] = bp[j];
      #pragma unroll 1
      for (int o = 0; o < 8; ++o){
        float a24[24];                              // R[o,i,f] = a24[i*3+f]
        const float* __restrict__ b3o = b3 + o * 24;
        #pragma unroll
        for (int j = 0; j < 24; ++j) a24[j] = b3o[j];
        #pragma unroll 1
        for (int c = 0; c < 4; ++c){                // m-chunks of 8
          float hh[8];
          #pragma unroll
          for (int j = 0; j < 8; ++j) hh[j] = A[c*8 + j];
          const float* __restrict__ rb = w3 + c * 1536 + o * 24;
          #pragma unroll
          for (int jj = 0; jj < 8; ++jj){
            const float* __restrict__ r = rb + jj * 192;    // 24-contig segment
            #pragma unroll
            for (int j = 0; j < 24; ++j) a24[j] = fmaf(hh[jj], r[j], a24[j]);
          }
        }
        // D[q,f] = sum_i R[o,i,f] * s1[i,q]
        float D[9];
        #pragma unroll
        for (int q = 0; q < 3; ++q){
          #pragma unroll
          for (int f = 0; f < 3; ++f){
            float t = 0.f;
            #pragma unroll
            for (int i = 0; i < 8; ++i) t = fmaf(a24[i*3 + f], s1[i*3 + q], t);
            D[q*3 + f] = t;
          }
        }
        #pragma unroll
        for (int pp2 = 0; pp2 < 3; ++pp2){
          float t = 0.f;
          #pragma unroll
          for (int q = 0; q < 3; ++q){
            #pragma unroll
            for (int f = 0; f < 3; ++f)
              t = fmaf(Bv[pp2*9 + q*3 + f], D[q*3 + f], t);
          }
          A[32 + o*3 + pp2] += t;                   // dynamic-o LDS r-m-w (cheap)
        }
      }
    }
  }

  // ---- store out0: [E,8,1] f32, contiguous 32 B/thread ----
  {
    float* o0 = out + (size_t)e * 8;
    ((float4*)o0)[0] = make_float4(msg0[0], msg0[1], msg0[2], msg0[3]);
    ((float4*)o0)[1] = make_float4(msg0[4], msg0[5], msg0[6], msg0[7]);
  }
  // ---- store out1: [E,8,3] f32, 96 B contiguous/thread (back-to-back -> L2 merges) ----
  {
    float m1[24];
    #pragma unroll
    for (int j = 0; j < 24; ++j) m1[j] = A[32 + j];
    float* o1 = out + (size_t)E_TOT * 8 + (size_t)e * 24;
    #pragma unroll
    for (int j = 0; j < 6; ++j)
      ((float4*)o1)[j] = make_float4(m1[4*j+0], m1[4*j+1], m1[4*j+2], m1[4*j+3]);
  }
}

extern "C" void kernel_launch(void* const* d_in, const int* in_sizes, int n_in,
                              void* d_out, int out_size, void* d_ws, size_t ws_size,
                              hipStream_t stream)
{
  const float* feat0 = (const float*)d_in[0];
  const float* feat1 = (const float*)d_in[1];
  const float* wE    = (const float*)d_in[2];
  const float* rad   = (const float*)d_in[3];
  const float* b00   = (const float*)d_in[4];
  const float* b01   = (const float*)d_in[11];
  const float* b10   = (const float*)d_in[18];
  const float* b11   = (const float*)d_in[25];
  const int* sidx    = (const int*)d_in[32];

  P4 W[4];
  for (int p = 0; p < 4; ++p){
    W[p].w1 = (const float*)d_in[5  + 7*p];
    W[p].b1 = (const float*)d_in[6  + 7*p];
    W[p].w2 = (const float*)d_in[7  + 7*p];
    W[p].b2 = (const float*)d_in[8  + 7*p];
    W[p].w3 = (const float*)d_in[9  + 7*p];
    W[p].b3 = (const float*)d_in[10 + 7*p];
  }

  edge_kernel<<<NBLK, TPB, 0, stream>>>(feat0, feat1, wE, rad, b00, b01, b10, b11,
                                        sidx, W[0], W[1], W[2], W[3], (float*)d_out);
}